// Round 4
// baseline (363.058 us; speedup 1.0000x reference)
//
#include <hip/hip_runtime.h>
#include <math.h>

// S4D forward (conv mode) via chunked linear recurrence.
// y[b,l,d] = D[d]*x[b,l,d] + sum_n CB[d,n] * h_n[l],  h_n[l] = a_n h_n[l-1] + x[l]
// a = exp(dt*A), CB = C * expm1(dt*A)/A * B, A_n = -0.5*(n+1)
//
// Block = 4 waves = 4 chunks x 64 d-lanes; coefficient slice (64n x 64d x
// {a,cb} = 32 KB) staged in LDS once per block. u/s states stored bf16.
// P0 coef:  acb[n][d]={a,cb} interleaved fp32 + aT[n][d]=a^64 fp32.
// P1 state: chunk-local end states (zero init), h[64] in regs, ds_read a.
// P2 scan:  s[c+1] = aT*s[c] + u[c] over 32 chunks, bf16 in/out, fp32 carry.
// P3 out:   h init = s_start(bf16), recurrence + cb-dot + D-skip, y once.

namespace {
constexpr int kBatch = 8;
constexpr int kLen   = 2048;
constexpr int kD     = 1024;
constexpr int kN     = 64;         // states
constexpr int kT     = 64;         // chunk length
constexpr int kTT    = 16;         // t-tile
constexpr int kC     = kLen / kT;  // 32 chunks

constexpr long kUElems = (long)kBatch * kC * kN * kD;  // 16,777,216 bf16
constexpr long kUBytes = kUElems * 2;                  // 33,554,432 B
// after u: acb fp32 (2*64*1024 floats), then aT fp32 (64*1024 floats)
}  // namespace

__device__ __forceinline__ unsigned short f2bf(float f) {
  unsigned u = __builtin_bit_cast(unsigned, f);
  u += 0x7fffu + ((u >> 16) & 1u);  // round-nearest-even
  return (unsigned short)(u >> 16);
}
__device__ __forceinline__ float bf2f(unsigned short h) {
  unsigned u = ((unsigned)h) << 16;
  return __builtin_bit_cast(float, u);
}

__global__ void s4d_coef_kernel(const float* __restrict__ log_dt,
                                const float* __restrict__ Bm,
                                const float* __restrict__ Cm,
                                float* __restrict__ acb,
                                float* __restrict__ aTt) {
  int tid = blockIdx.x * blockDim.x + threadIdx.x;  // 65536 threads
  int d = tid & (kD - 1);
  int n = tid >> 10;
  float dt  = expf(log_dt[d]);
  float An  = -0.5f * (float)(n + 1);
  float dtA = dt * An;
  float a   = expf(dtA);
  float bbar = (expm1f(dtA) / An) * Bm[d * kN + n];
  float cb   = Cm[d * kN + n] * bbar;
  float aT   = expf(dtA * (float)kT);  // a^64
  acb[2L * ((long)n * kD + d)]     = a;
  acb[2L * ((long)n * kD + d) + 1] = cb;
  aTt[(long)n * kD + d] = aT;
}

// Phase 1: chunk-local end states only (zero initial state).
__global__ __launch_bounds__(256, 4) void s4d_state_kernel(
    const float* __restrict__ x, const float* __restrict__ acb,
    unsigned short* __restrict__ u) {
  __shared__ float lds[kN * 64 * 2];  // [n][lane][{a,cb}] = 32 KB
  int tidb = threadIdx.x;
  int db = blockIdx.x & 15;          // d-block (64 d each)
  int c4 = (blockIdx.x >> 4) & 7;    // chunk group of 4
  int b  = blockIdx.x >> 7;

  // stage coefficient slice: 2048 float4
  const float4* g4 = (const float4*)acb;
  float4* l4 = (float4*)lds;
#pragma unroll
  for (int i = 0; i < 8; ++i) {
    int idx = i * 256 + tidb;
    int n = idx >> 5, j = idx & 31;
    l4[idx] = g4[n * 512 + db * 32 + j];
  }
  __syncthreads();

  int wave = tidb >> 6, lane = tidb & 63;
  int c = c4 * 4 + wave;
  int d = db * 64 + lane;
  const float* xp = x + ((long)b * kLen + (long)c * kT) * kD + d;

  float h[kN];
#pragma unroll
  for (int n = 0; n < kN; ++n) h[n] = 0.f;

#pragma unroll 1
  for (int tt = 0; tt < kT / kTT; ++tt) {
    float xv[kTT];
#pragma unroll
    for (int t = 0; t < kTT; ++t) xv[t] = xp[(long)(tt * kTT + t) * kD];
#pragma unroll
    for (int t = 0; t < kTT; ++t) asm volatile("" : "+v"(xv[t]));  // pin
#pragma unroll 16
    for (int n = 0; n < kN; ++n) {
      float a = lds[n * 128 + lane * 2];  // ds_read_b32, 2-way alias (free)
      float hn = h[n];
#pragma unroll
      for (int t = 0; t < kTT; ++t) hn = fmaf(hn, a, xv[t]);
      h[n] = hn;
    }
  }
  unsigned short* up = u + ((long)(b * kC + c) * kN) * kD + d;
#pragma unroll
  for (int n = 0; n < kN; ++n) up[(long)n * kD] = f2bf(h[n]);
}

// Phase 2: inter-chunk scan. After this the u-region holds s_start[c] =
// state at the END of chunk c-1 (initial state for chunk c), bf16.
__global__ void s4d_scan_kernel(const float* __restrict__ aTt,
                                unsigned short* __restrict__ u) {
  int tid = blockIdx.x * blockDim.x + threadIdx.x;  // 524288 threads
  int d  = tid & (kD - 1);
  int bn = tid >> 10;
  int n  = bn & (kN - 1);
  int b  = bn >> 6;
  float aT = aTt[(long)n * kD + d];
  unsigned short* up = u + ((long)b * kC * kN + n) * kD + d;
  const long cs = (long)kN * kD;
  float s = 0.f;
#pragma unroll 1
  for (int c = 0; c < kC; ++c) {
    float uv = bf2f(up[(long)c * cs]);
    up[(long)c * cs] = f2bf(s);  // in place: u[c] -> s_start[c]
    s = fmaf(aT, s, uv);
  }
}

// Phase 3: full output. Recurrence with scanned initial state, y written once.
__global__ __launch_bounds__(256, 4) void s4d_out_kernel(
    const float* __restrict__ x, const float* __restrict__ Dv,
    const float* __restrict__ acb, const unsigned short* __restrict__ u,
    float* __restrict__ y) {
  __shared__ float lds[kN * 64 * 2];  // [n][lane][{a,cb}] = 32 KB
  int tidb = threadIdx.x;
  int db = blockIdx.x & 15;
  int c4 = (blockIdx.x >> 4) & 7;
  int b  = blockIdx.x >> 7;

  const float4* g4 = (const float4*)acb;
  float4* l4 = (float4*)lds;
#pragma unroll
  for (int i = 0; i < 8; ++i) {
    int idx = i * 256 + tidb;
    int n = idx >> 5, j = idx & 31;
    l4[idx] = g4[n * 512 + db * 32 + j];
  }
  __syncthreads();

  int wave = tidb >> 6, lane = tidb & 63;
  int c = c4 * 4 + wave;
  int d = db * 64 + lane;

  const unsigned short* sp = u + ((long)(b * kC + c) * kN) * kD + d;
  float h[kN];
#pragma unroll
  for (int n = 0; n < kN; ++n) h[n] = bf2f(sp[(long)n * kD]);

  float Dd = Dv[d];
  const float* xp = x + ((long)b * kLen + (long)c * kT) * kD + d;
  float*       yp = y + ((long)b * kLen + (long)c * kT) * kD + d;

#pragma unroll 1
  for (int tt = 0; tt < kT / kTT; ++tt) {
    float xv[kTT];
#pragma unroll
    for (int t = 0; t < kTT; ++t) xv[t] = xp[(long)(tt * kTT + t) * kD];
#pragma unroll
    for (int t = 0; t < kTT; ++t) asm volatile("" : "+v"(xv[t]));  // pin
    float acc[kTT];
#pragma unroll
    for (int t = 0; t < kTT; ++t) acc[t] = Dd * xv[t];
#pragma unroll 16
    for (int n = 0; n < kN; ++n) {
      float a  = lds[n * 128 + lane * 2];
      float cb = lds[n * 128 + lane * 2 + 1];
      float hn = h[n];
#pragma unroll
      for (int t = 0; t < kTT; ++t) {
        hn = fmaf(hn, a, xv[t]);
        acc[t] = fmaf(cb, hn, acc[t]);
      }
      h[n] = hn;
    }
#pragma unroll
    for (int t = 0; t < kTT; ++t) yp[(long)(tt * kTT + t) * kD] = acc[t];
  }
}

extern "C" void kernel_launch(void* const* d_in, const int* in_sizes, int n_in,
                              void* d_out, int out_size, void* d_ws, size_t ws_size,
                              hipStream_t stream) {
  const float* x      = (const float*)d_in[0];
  const float* log_dt = (const float*)d_in[1];
  const float* Bm     = (const float*)d_in[2];
  const float* Cm     = (const float*)d_in[3];
  const float* Dv     = (const float*)d_in[4];
  float* y = (float*)d_out;

  unsigned short* u = (unsigned short*)d_ws;
  float* acb = (float*)((char*)d_ws + kUBytes);       // 131072 floats
  float* aTt = acb + 2L * kN * kD;                    // 65536 floats

  hipLaunchKernelGGL(s4d_coef_kernel, dim3((kN * kD) / 256), dim3(256), 0, stream,
                     log_dt, Bm, Cm, acb, aTt);
  hipLaunchKernelGGL(s4d_state_kernel, dim3(kBatch * (kC / 4) * (kD / 64)), dim3(256), 0,
                     stream, x, acb, u);
  hipLaunchKernelGGL(s4d_scan_kernel, dim3((kBatch * kN * kD) / 256), dim3(256), 0, stream,
                     aTt, u);
  hipLaunchKernelGGL(s4d_out_kernel, dim3(kBatch * (kC / 4) * (kD / 64)), dim3(256), 0,
                     stream, x, Dv, acb, u, y);
}